// Round 6
// baseline (619.033 us; speedup 1.0000x reference)
//
#include <hip/hip_runtime.h>
#include <hip/hip_fp16.h>
#include <stdint.h>

#define B_ROWS 4096
#define N_PAT  8192
#define N_NEU  1024

typedef _Float16 f16x8 __attribute__((ext_vector_type(8)));
typedef _Float16 f16x4 __attribute__((ext_vector_type(4)));
typedef float    f32x4 __attribute__((ext_vector_type(4)));

// ---------------- fp32 -> fp16 elementwise convert (vectorized) ----------------
__global__ __launch_bounds__(256) void convert_f32_f16(
    const float* __restrict__ in, _Float16* __restrict__ out, int n4) {
  int idx    = blockIdx.x * 256 + threadIdx.x;
  int stride = gridDim.x * 256;
  for (int i = idx; i < n4; i += stride) {
    float4 v = reinterpret_cast<const float4*>(in)[i];
    f16x4 h  = { (_Float16)v.x, (_Float16)v.y, (_Float16)v.z, (_Float16)v.w };
    reinterpret_cast<f16x4*>(out)[i] = h;
  }
}

// ---------------- fp32 [rows][cols] -> fp16 transpose [cols][rows] ----------------
__global__ __launch_bounds__(256) void transpose_f32_f16(
    const float* __restrict__ in, _Float16* __restrict__ out, int rows, int cols) {
  __shared__ float tile[32][33];
  int c0 = blockIdx.x * 32, r0 = blockIdx.y * 32;
  int tx = threadIdx.x, ty = threadIdx.y;  // 32 x 8
  #pragma unroll
  for (int i = 0; i < 32; i += 8)
    tile[ty + i][tx] = in[(size_t)(r0 + ty + i) * cols + c0 + tx];
  __syncthreads();
  #pragma unroll
  for (int i = 0; i < 32; i += 8)
    out[(size_t)(c0 + ty + i) * rows + r0 + tx] = (_Float16)tile[tx][ty + i];
}

// ---------------- async global->LDS, 16B per lane, wave-uniform LDS base ----------------
__device__ __forceinline__ void gload_lds16(const _Float16* g, _Float16* l) {
  __builtin_amdgcn_global_load_lds(
      (const __attribute__((address_space(1))) uint32_t*)g,
      (__attribute__((address_space(3))) uint32_t*)l, 16, 0, 0);
}

// ---------------- C[z][M,N] = A[M,k0:k1] @ Bt[N,k0:k1]^T ----------------
// 128x128 tile, BK=32, double-buffered LDS, issue-early staging, and T4
// counted vmcnt: per K-step we wait vmcnt(4) (tile t landed; tile t+1 in
// flight) instead of __syncthreads' vmcnt(0) drain of the just-issued loads.
// Barrier ledger (2 raw barriers/iter):
//   B1 (after per-wave vmcnt(4)): all waves' tile-t loads are in LDS -> reads ok.
//   B2 (after MFMA): all waves done reading slot c before iter i+1 stages into it.
// Every ds_read result feeds an MFMA, so lgkm is drained by use-waits before B2.
// 3-4 blocks/CU resident -> cross-block overlap hides residual latency (m114).
template <typename OUT_T>
__global__ __launch_bounds__(256, 4) void gemm_bt_db(
    const _Float16* __restrict__ A, const _Float16* __restrict__ Bt,
    OUT_T* __restrict__ C, int M, int N, int K, int KS) {
  __shared__ _Float16 As[2][128 * 32];
  __shared__ _Float16 Bs[2][128 * 32];
  const int t    = threadIdx.x;
  const int lane = t & 63;
  const int w    = t >> 6;
  const int wr   = w >> 1;
  const int wc   = w & 1;
  const int m0   = blockIdx.x * 128;
  const int n0   = blockIdx.y * 128;
  const int k0   = blockIdx.z * KS;

  const int srow = w * 16 + (lane >> 2);
  const int scol = (lane & 3) * 8;
  const _Float16* gA = A  + (size_t)(m0 + srow) * K + scol + k0;
  const _Float16* gB = Bt + (size_t)(n0 + srow) * K + scol + k0;
  const size_t jump = (size_t)64 * K;

  const int lrow = lane & 15;
  const int kg   = lane >> 4;
  const int nt   = KS / 32;

  f32x4 acc[4][4] = {};

  // prologue: stage tile 0 into buffer 0 (no wait here; loop iter 0 waits)
  {
    _Float16* lA = &As[0][w * 512];
    _Float16* lB = &Bs[0][w * 512];
    gload_lds16(gA, lA);
    gload_lds16(gA + jump, lA + 2048);
    gload_lds16(gB, lB);
    gload_lds16(gB + jump, lB + 2048);
  }

  for (int it = 0; it < nt; ++it) {
    const int cur = it & 1;
    // issue next tile's loads early (into the other buffer)
    if (it + 1 < nt) {
      const int kt = (it + 1) * 32;
      _Float16* lA = &As[cur ^ 1][w * 512];
      _Float16* lB = &Bs[cur ^ 1][w * 512];
      gload_lds16(gA + kt, lA);
      gload_lds16(gA + jump + kt, lA + 2048);
      gload_lds16(gB + kt, lB);
      gload_lds16(gB + jump + kt, lB + 2048);
      asm volatile("s_waitcnt vmcnt(4)" ::: "memory");  // tile t landed; t+1 in flight
    } else {
      asm volatile("s_waitcnt vmcnt(0)" ::: "memory");  // pipeline epilogue
    }
    __builtin_amdgcn_s_barrier();        // B1: staging of tile t visible to all waves
    __builtin_amdgcn_sched_barrier(0);

    f16x8 af[4], bf[4];
    #pragma unroll
    for (int mi = 0; mi < 4; ++mi)
      af[mi] = *reinterpret_cast<const f16x8*>(&As[cur][(wr * 64 + mi * 16 + lrow) * 32 + kg * 8]);
    #pragma unroll
    for (int ni = 0; ni < 4; ++ni)
      bf[ni] = *reinterpret_cast<const f16x8*>(&Bs[cur][(wc * 64 + ni * 16 + lrow) * 32 + kg * 8]);
    #pragma unroll
    for (int mi = 0; mi < 4; ++mi) {
      #pragma unroll
      for (int ni = 0; ni < 4; ++ni)
        acc[mi][ni] = __builtin_amdgcn_mfma_f32_16x16x32_f16(af[mi], bf[ni], acc[mi][ni], 0, 0, 0);
    }
    __builtin_amdgcn_s_barrier();        // B2: slot cur free for iter i+1's staging
    __builtin_amdgcn_sched_barrier(0);
  }

  OUT_T* Cz = C + (size_t)blockIdx.z * M * N;
  const int crow = (lane >> 4) * 4;
  const int ccol = lane & 15;
  #pragma unroll
  for (int mi = 0; mi < 4; ++mi) {
    #pragma unroll
    for (int ni = 0; ni < 4; ++ni) {
      #pragma unroll
      for (int r = 0; r < 4; ++r) {
        int row = m0 + wr * 64 + mi * 16 + crow + r;
        int col = n0 + wc * 64 + ni * 16 + ccol;
        Cz[(size_t)row * N + col] = (OUT_T)acc[mi][ni][r];
      }
    }
  }
}

// ---------------- sum SPLIT fp32 partials -> OUT_T ----------------
template <typename OUT_T, int SPLIT>
__global__ __launch_bounds__(256) void reduce_partials(
    const float* __restrict__ Cp, OUT_T* __restrict__ out, int n4, int stride4) {
  int idx    = blockIdx.x * 256 + threadIdx.x;
  int stride = gridDim.x * 256;
  for (int i = idx; i < n4; i += stride) {
    float4 a = reinterpret_cast<const float4*>(Cp)[i];
    #pragma unroll
    for (int s = 1; s < SPLIT; ++s) {
      float4 b = reinterpret_cast<const float4*>(Cp)[(size_t)s * stride4 + i];
      a.x += b.x; a.y += b.y; a.z += b.z; a.w += b.w;
    }
    if constexpr (sizeof(OUT_T) == 2) {
      f16x4 h = { (_Float16)a.x, (_Float16)a.y, (_Float16)a.z, (_Float16)a.w };
      reinterpret_cast<f16x4*>(out)[i] = h;
    } else {
      reinterpret_cast<float4*>(out)[i] = a;
    }
  }
}

// ---------------- in-place row softmax over N=8192 fp16 scores ----------------
__global__ __launch_bounds__(256) void softmax_rows(_Float16* __restrict__ S, int N) {
  const int t = threadIdx.x;
  f16x8* pv = reinterpret_cast<f16x8*>(S + (size_t)blockIdx.x * N);
  float v[32];
  float m = -3.0e38f;
  #pragma unroll
  for (int i = 0; i < 4; ++i) {
    f16x8 h = pv[i * 256 + t];
    #pragma unroll
    for (int e = 0; e < 8; ++e) {
      float f = (float)h[e];
      v[i * 8 + e] = f;
      m = fmaxf(m, f);
    }
  }
  #pragma unroll
  for (int o = 32; o; o >>= 1) m = fmaxf(m, __shfl_xor(m, o));
  __shared__ float redm[4];
  if ((t & 63) == 0) redm[t >> 6] = m;
  __syncthreads();
  m = fmaxf(fmaxf(redm[0], redm[1]), fmaxf(redm[2], redm[3]));

  float s = 0.f;
  #pragma unroll
  for (int i = 0; i < 32; ++i) { v[i] = __expf(v[i] - m); s += v[i]; }
  #pragma unroll
  for (int o = 32; o; o >>= 1) s += __shfl_xor(s, o);
  __shared__ float reds[4];
  if ((t & 63) == 0) reds[t >> 6] = s;
  __syncthreads();
  s = reds[0] + reds[1] + reds[2] + reds[3];
  const float inv = 1.0f / s;

  #pragma unroll
  for (int i = 0; i < 4; ++i) {
    f16x8 h;
    #pragma unroll
    for (int e = 0; e < 8; ++e) h[e] = (_Float16)(v[i * 8 + e] * inv);
    pv[i * 256 + t] = h;
  }
}

extern "C" void kernel_launch(void* const* d_in, const int* in_sizes, int n_in,
                              void* d_out, int out_size, void* d_ws, size_t ws_size,
                              hipStream_t stream) {
  const float* x        = (const float*)d_in[0];
  const float* patterns = (const float*)d_in[1];
  float* out            = (float*)d_out;
  char* ws = (char*)d_ws;

  _Float16* Xb   = (_Float16*)(ws);                          //   8 MB [4096][1024]
  _Float16* Pb   = (_Float16*)(ws + ((size_t)8  << 20));     //  16 MB [8192][1024]
  _Float16* PbT  = (_Float16*)(ws + ((size_t)24 << 20));     //  16 MB [1024][8192]
  _Float16* S    = (_Float16*)(ws + ((size_t)40 << 20));     //  64 MB [4096][8192]
  float*    part = (float*)   (ws + ((size_t)104 << 20));    //  split x 16 MB fp32 partials

  const size_t base = (size_t)104 << 20;
  const int split = (ws_size >= base + ((size_t)64 << 20)) ? 4
                  : (ws_size >= base + ((size_t)32 << 20)) ? 2 : 1;

  convert_f32_f16<<<dim3(1024), dim3(256), 0, stream>>>(x, Xb, (B_ROWS * N_NEU) / 4);
  convert_f32_f16<<<dim3(2048), dim3(256), 0, stream>>>(patterns, Pb, (N_PAT * N_NEU) / 4);
  transpose_f32_f16<<<dim3(N_NEU / 32, N_PAT / 32), dim3(32, 8), 0, stream>>>(patterns, PbT, N_PAT, N_NEU);

  const int n4 = (B_ROWS * N_NEU) / 4;
  const int stride4 = n4;

  for (int it = 0; it < 3; ++it) {
    // scores = Xb @ Pb^T  (TEMPERATURE == 1.0)  M=4096 N=8192 K=1024
    gemm_bt_db<_Float16><<<dim3(B_ROWS / 128, N_PAT / 128, 1), dim3(256), 0, stream>>>(
        Xb, Pb, S, B_ROWS, N_PAT, N_NEU, N_NEU);
    softmax_rows<<<dim3(B_ROWS), dim3(256), 0, stream>>>(S, N_PAT);

    // new_x = probs @ P == probs @ (PbT)^T   (M=4096, N=1024, K=8192)
    if (split > 1) {
      gemm_bt_db<float><<<dim3(B_ROWS / 128, N_NEU / 128, split), dim3(256), 0, stream>>>(
          S, PbT, part, B_ROWS, N_NEU, N_PAT, N_PAT / split);
      if (it < 2) {
        if (split == 4)
          reduce_partials<_Float16, 4><<<dim3(2048), dim3(256), 0, stream>>>(part, Xb, n4, stride4);
        else
          reduce_partials<_Float16, 2><<<dim3(2048), dim3(256), 0, stream>>>(part, Xb, n4, stride4);
      } else {
        if (split == 4)
          reduce_partials<float, 4><<<dim3(2048), dim3(256), 0, stream>>>(part, out, n4, stride4);
        else
          reduce_partials<float, 2><<<dim3(2048), dim3(256), 0, stream>>>(part, out, n4, stride4);
      }
    } else {
      gemm_bt_db<float><<<dim3(B_ROWS / 128, N_NEU / 128, 1), dim3(256), 0, stream>>>(
          S, PbT, part, B_ROWS, N_NEU, N_PAT, N_PAT);
      if (it < 2)
        reduce_partials<_Float16, 1><<<dim3(2048), dim3(256), 0, stream>>>(part, Xb, n4, stride4);
      else
        reduce_partials<float, 1><<<dim3(2048), dim3(256), 0, stream>>>(part, out, n4, stride4);
    }
  }
}

// Round 7
// 601.861 us; speedup vs baseline: 1.0285x; 1.0285x over previous
//
#include <hip/hip_runtime.h>
#include <hip/hip_fp16.h>
#include <stdint.h>

#define B_ROWS 4096
#define N_PAT  8192
#define N_NEU  1024

typedef _Float16 f16x8 __attribute__((ext_vector_type(8)));
typedef _Float16 f16x4 __attribute__((ext_vector_type(4)));
typedef float    f32x4 __attribute__((ext_vector_type(4)));

__device__ __forceinline__ f32x4 mfma16(f16x8 a, f16x8 b, f32x4 c) {
  return __builtin_amdgcn_mfma_f32_16x16x32_f16(a, b, c, 0, 0, 0);
}

// ---------------- fp32 -> fp16 elementwise convert (vectorized) ----------------
__global__ __launch_bounds__(256) void convert_f32_f16(
    const float* __restrict__ in, _Float16* __restrict__ out, int n4) {
  int idx    = blockIdx.x * 256 + threadIdx.x;
  int stride = gridDim.x * 256;
  for (int i = idx; i < n4; i += stride) {
    float4 v = reinterpret_cast<const float4*>(in)[i];
    f16x4 h  = { (_Float16)v.x, (_Float16)v.y, (_Float16)v.z, (_Float16)v.w };
    reinterpret_cast<f16x4*>(out)[i] = h;
  }
}

// ---------------- fp32 [rows][cols] -> fp16 transpose [cols][rows] ----------------
__global__ __launch_bounds__(256) void transpose_f32_f16(
    const float* __restrict__ in, _Float16* __restrict__ out, int rows, int cols) {
  __shared__ float tile[32][33];
  int c0 = blockIdx.x * 32, r0 = blockIdx.y * 32;
  int tx = threadIdx.x, ty = threadIdx.y;  // 32 x 8
  #pragma unroll
  for (int i = 0; i < 32; i += 8)
    tile[ty + i][tx] = in[(size_t)(r0 + ty + i) * cols + c0 + tx];
  __syncthreads();
  #pragma unroll
  for (int i = 0; i < 32; i += 8)
    out[(size_t)(c0 + ty + i) * rows + r0 + tx] = (_Float16)tile[tx][ty + i];
}

// ---------------- async global->LDS, 16B per lane, wave-uniform LDS base ----------------
__device__ __forceinline__ void gload_lds16(const _Float16* g, _Float16* l) {
  __builtin_amdgcn_global_load_lds(
      (const __attribute__((address_space(1))) uint32_t*)g,
      (__attribute__((address_space(3))) uint32_t*)l, 16, 0, 0);
}

// ================= 256x256 tile, 8 waves, fragment-linear LDS, phase-split =================
// C[z][M,N] = A[M,k0:k1] @ Bt[N,k0:k1]^T. BK=64, 2 LDS K-tile buffers (128 KiB).
//
// LDS holds each half-tile (128 rows x 64 k) in MFMA-FRAGMENT-LINEAR order:
//   elem (fr*2+ks)*512 + lane*8 + j  ==  half[fr*16 + (lane&15)][ks*32 + (lane>>4)*8 + j]
// Staged by global_load_lds (linear LDS dest = tid*16B) with the per-thread global
// source pre-permuted:  q=g*8+(t>>6); row=(q>>1)*16+(t&15); col=(q&1)*32+((t>>4)&3)*8.
// => every ds_read_b128 fragment load is a lane-contiguous 1KB block: conflict-free
// (2 lanes/bank), vs the ~8-way conflict of any [row][col] layout at 64/128B row stride.
//
// Schedule per K-tile (buf = tt&1):
//   GATE: s_waitcnt vmcnt(0)  (per-wave: own stage loads for THIS tile, issued one
//         tile ago, are in LDS)  ->  s_barrier (cross-wave visibility)
//   p0: stage A-halves of tile t+1 into buf^1 ; ds_read bf(8)+af(4) ; MFMA x16 ; bar
//   p1: stage B-halves of tile t+1            ; ds_read af(4)       ; MFMA x16 ; bar
//   p2:                                         ds_read af(4)       ; MFMA x16 ; bar
//   p3:                                         ds_read af(4)       ; MFMA x16 ; bar
// Ledger: stage of tile t+1 writes buf^1, which tile t-1 finished reading before
// this tile's gate barrier; reads of buf gated by vmcnt(0)+barrier. The vmcnt(0)
// drain is ~free: those loads were issued >=3 phases (~1800 cyc) earlier.
template <typename OUT_T>
__global__ __launch_bounds__(512, 2) void gemm_8p(
    const _Float16* __restrict__ A, const _Float16* __restrict__ Bt,
    OUT_T* __restrict__ C, int M, int N, int K, int KS) {
  __shared__ _Float16 lds_[2][2][2][8192];  // [buf][mat][half][frag-linear]
  _Float16* const L = &lds_[0][0][0][0];
  const int t    = threadIdx.x;
  const int lane = t & 63;
  const int w    = t >> 6;       // wave 0..7
  const int wr   = w >> 2;       // M half -> wave tile 128x64
  const int wc   = w & 3;        // N quarter
  const int m0   = blockIdx.x * 256;
  const int n0   = blockIdx.y * 256;
  const int k0   = blockIdx.z * KS;

  // staging source (fragment-order permutation of the half-tile)
  const int r16  = t & 15;
  const int kgq  = (t >> 4) & 3;
  const int qq   = t >> 6;
  const int colo = (qq & 1) * 32 + kgq * 8;
  const int frow = (qq >> 1) * 16 + r16;
  const _Float16* sA = A  + (size_t)(m0 + frow) * K + colo + k0;
  const _Float16* sB = Bt + (size_t)(n0 + frow) * K + colo + k0;
  const size_t gj = (size_t)64 * K;    // g=1 jump (64 rows)
  const size_t hj = (size_t)128 * K;   // half jump

  const int bfr = (wc & 1) * 4;        // B frag-row base within its half
  const int NT  = KS >> 6;

  // LDS read bases (arithmetic, no runtime-indexed arrays -> no scratch)
  const int aOff = (wr << 13);                    // A: mat 0, half wr
  const int bOff = 16384 + ((wc >> 1) << 13);     // B: mat 1, half wc>>1
  const int rdo  = lane * 8;

  f32x4 acc[8][4] = {};

  auto stageA = [&](int bufn, int kt) {
    _Float16* d = L + (bufn << 15) + w * 512;
    gload_lds16(sA + kt,           d);
    gload_lds16(sA + gj + kt,      d + 4096);
    gload_lds16(sA + hj + kt,      d + 8192);
    gload_lds16(sA + hj + gj + kt, d + 12288);
  };
  auto stageB = [&](int bufn, int kt) {
    _Float16* d = L + (bufn << 15) + 16384 + w * 512;
    gload_lds16(sB + kt,           d);
    gload_lds16(sB + gj + kt,      d + 4096);
    gload_lds16(sB + hj + kt,      d + 8192);
    gload_lds16(sB + hj + gj + kt, d + 12288);
  };

#define LD_A(Ah, MI, KSL) \
  (*reinterpret_cast<const f16x8*>(&(Ah)[(((MI) * 2 + (KSL)) << 9) + rdo]))

#define DO_PHASE(MI0)                                                        \
  {                                                                          \
    f16x8 a0 = LD_A(Ah, MI0, 0), a1 = LD_A(Ah, MI0, 1);                      \
    f16x8 a2 = LD_A(Ah, (MI0) + 1, 0), a3 = LD_A(Ah, (MI0) + 1, 1);          \
    __builtin_amdgcn_s_setprio(1);                                           \
    _Pragma("unroll")                                                        \
    for (int ni = 0; ni < 4; ++ni) {                                         \
      acc[MI0][ni]       = mfma16(a0, bf[ni][0], acc[MI0][ni]);              \
      acc[MI0][ni]       = mfma16(a1, bf[ni][1], acc[MI0][ni]);              \
      acc[(MI0) + 1][ni] = mfma16(a2, bf[ni][0], acc[(MI0) + 1][ni]);        \
      acc[(MI0) + 1][ni] = mfma16(a3, bf[ni][1], acc[(MI0) + 1][ni]);        \
    }                                                                        \
    __builtin_amdgcn_s_setprio(0);                                           \
    __builtin_amdgcn_s_barrier();                                            \
  }

  // prologue: stage tile 0 -> buf 0
  stageA(0, 0);
  stageB(0, 0);

  for (int tt = 0; tt < NT; ++tt) {
    const int buf = tt & 1;
    const _Float16* Ah = L + (buf << 15) + aOff;
    const _Float16* Bh = L + (buf << 15) + bOff;

    // ---- tile gate: own loads for this tile drained, then cross-wave barrier
    asm volatile("s_waitcnt vmcnt(0)" ::: "memory");
    __builtin_amdgcn_s_barrier();
    __builtin_amdgcn_sched_barrier(0);

    const bool pre = (tt + 1 < NT);
    const int kt1  = (tt + 1) << 6;

    // ---- p0: stage next A, read bf + af quadrant 0
    if (pre) stageA(buf ^ 1, kt1);
    f16x8 bf[4][2];
    #pragma unroll
    for (int ni = 0; ni < 4; ++ni) {
      bf[ni][0] = *reinterpret_cast<const f16x8*>(&Bh[(((bfr + ni) * 2 + 0) << 9) + rdo]);
      bf[ni][1] = *reinterpret_cast<const f16x8*>(&Bh[(((bfr + ni) * 2 + 1) << 9) + rdo]);
    }
    DO_PHASE(0)
    // ---- p1: stage next B, quadrant 1
    if (pre) stageB(buf ^ 1, kt1);
    DO_PHASE(2)
    // ---- p2, p3
    DO_PHASE(4)
    DO_PHASE(6)
  }

  OUT_T* Cz = C + (size_t)blockIdx.z * M * N;
  const int crow = (lane >> 4) * 4;
  const int ccol = lane & 15;
  #pragma unroll
  for (int mi = 0; mi < 8; ++mi) {
    #pragma unroll
    for (int ni = 0; ni < 4; ++ni) {
      #pragma unroll
      for (int r = 0; r < 4; ++r) {
        int row = m0 + wr * 128 + mi * 16 + crow + r;
        int col = n0 + wc * 64 + ni * 16 + ccol;
        Cz[(size_t)row * N + col] = (OUT_T)acc[mi][ni][r];
      }
    }
  }
#undef LD_A
#undef DO_PHASE
}

// ---------------- sum SPLIT fp32 partials -> OUT_T ----------------
template <typename OUT_T, int SPLIT>
__global__ __launch_bounds__(256) void reduce_partials(
    const float* __restrict__ Cp, OUT_T* __restrict__ out, int n4, int stride4) {
  int idx    = blockIdx.x * 256 + threadIdx.x;
  int stride = gridDim.x * 256;
  for (int i = idx; i < n4; i += stride) {
    float4 a = reinterpret_cast<const float4*>(Cp)[i];
    #pragma unroll
    for (int s = 1; s < SPLIT; ++s) {
      float4 b = reinterpret_cast<const float4*>(Cp)[(size_t)s * stride4 + i];
      a.x += b.x; a.y += b.y; a.z += b.z; a.w += b.w;
    }
    if constexpr (sizeof(OUT_T) == 2) {
      f16x4 h = { (_Float16)a.x, (_Float16)a.y, (_Float16)a.z, (_Float16)a.w };
      reinterpret_cast<f16x4*>(out)[i] = h;
    } else {
      reinterpret_cast<float4*>(out)[i] = a;
    }
  }
}

// ---------------- in-place row softmax over N=8192 fp16 scores ----------------
__global__ __launch_bounds__(256) void softmax_rows(_Float16* __restrict__ S, int N) {
  const int t = threadIdx.x;
  f16x8* pv = reinterpret_cast<f16x8*>(S + (size_t)blockIdx.x * N);
  float v[32];
  float m = -3.0e38f;
  #pragma unroll
  for (int i = 0; i < 4; ++i) {
    f16x8 h = pv[i * 256 + t];
    #pragma unroll
    for (int e = 0; e < 8; ++e) {
      float f = (float)h[e];
      v[i * 8 + e] = f;
      m = fmaxf(m, f);
    }
  }
  #pragma unroll
  for (int o = 32; o; o >>= 1) m = fmaxf(m, __shfl_xor(m, o));
  __shared__ float redm[4];
  if ((t & 63) == 0) redm[t >> 6] = m;
  __syncthreads();
  m = fmaxf(fmaxf(redm[0], redm[1]), fmaxf(redm[2], redm[3]));

  float s = 0.f;
  #pragma unroll
  for (int i = 0; i < 32; ++i) { v[i] = __expf(v[i] - m); s += v[i]; }
  #pragma unroll
  for (int o = 32; o; o >>= 1) s += __shfl_xor(s, o);
  __shared__ float reds[4];
  if ((t & 63) == 0) reds[t >> 6] = s;
  __syncthreads();
  s = reds[0] + reds[1] + reds[2] + reds[3];
  const float inv = 1.0f / s;

  #pragma unroll
  for (int i = 0; i < 4; ++i) {
    f16x8 h;
    #pragma unroll
    for (int e = 0; e < 8; ++e) h[e] = (_Float16)(v[i * 8 + e] * inv);
    pv[i * 256 + t] = h;
  }
}

extern "C" void kernel_launch(void* const* d_in, const int* in_sizes, int n_in,
                              void* d_out, int out_size, void* d_ws, size_t ws_size,
                              hipStream_t stream) {
  const float* x        = (const float*)d_in[0];
  const float* patterns = (const float*)d_in[1];
  float* out            = (float*)d_out;
  char* ws = (char*)d_ws;

  _Float16* Xb   = (_Float16*)(ws);                          //   8 MB [4096][1024]
  _Float16* Pb   = (_Float16*)(ws + ((size_t)8  << 20));     //  16 MB [8192][1024]
  _Float16* PbT  = (_Float16*)(ws + ((size_t)24 << 20));     //  16 MB [1024][8192]
  _Float16* S    = (_Float16*)(ws + ((size_t)40 << 20));     //  64 MB [4096][8192]
  float*    part = (float*)   (ws + ((size_t)104 << 20));    //  split x 16 MB fp32 partials

  const size_t base = (size_t)104 << 20;
  const int split = (ws_size >= base + ((size_t)64 << 20)) ? 4
                  : (ws_size >= base + ((size_t)32 << 20)) ? 2 : 1;

  convert_f32_f16<<<dim3(1024), dim3(256), 0, stream>>>(x, Xb, (B_ROWS * N_NEU) / 4);
  convert_f32_f16<<<dim3(2048), dim3(256), 0, stream>>>(patterns, Pb, (N_PAT * N_NEU) / 4);
  transpose_f32_f16<<<dim3(N_NEU / 32, N_PAT / 32), dim3(32, 8), 0, stream>>>(patterns, PbT, N_PAT, N_NEU);

  const int n4 = (B_ROWS * N_NEU) / 4;
  const int stride4 = n4;

  for (int it = 0; it < 3; ++it) {
    // scores = Xb @ Pb^T  (TEMPERATURE == 1.0)  M=4096 N=8192 K=1024
    gemm_8p<_Float16><<<dim3(B_ROWS / 256, N_PAT / 256, 1), dim3(512), 0, stream>>>(
        Xb, Pb, S, B_ROWS, N_PAT, N_NEU, N_NEU);
    softmax_rows<<<dim3(B_ROWS), dim3(256), 0, stream>>>(S, N_PAT);

    // new_x = probs @ P == probs @ (PbT)^T   (M=4096, N=1024, K=8192)
    if (split > 1) {
      gemm_8p<float><<<dim3(B_ROWS / 256, N_NEU / 256, split), dim3(512), 0, stream>>>(
          S, PbT, part, B_ROWS, N_NEU, N_PAT, N_PAT / split);
      if (it < 2) {
        if (split == 4)
          reduce_partials<_Float16, 4><<<dim3(2048), dim3(256), 0, stream>>>(part, Xb, n4, stride4);
        else
          reduce_partials<_Float16, 2><<<dim3(2048), dim3(256), 0, stream>>>(part, Xb, n4, stride4);
      } else {
        if (split == 4)
          reduce_partials<float, 4><<<dim3(2048), dim3(256), 0, stream>>>(part, out, n4, stride4);
        else
          reduce_partials<float, 2><<<dim3(2048), dim3(256), 0, stream>>>(part, out, n4, stride4);
      }
    } else {
      gemm_8p<float><<<dim3(B_ROWS / 256, N_NEU / 256, 1), dim3(512), 0, stream>>>(
          S, PbT, part, B_ROWS, N_NEU, N_PAT, N_PAT);
      if (it < 2)
        reduce_partials<_Float16, 1><<<dim3(2048), dim3(256), 0, stream>>>(part, Xb, n4, stride4);
      else
        reduce_partials<float, 1><<<dim3(2048), dim3(256), 0, stream>>>(part, out, n4, stride4);
    }
  }
}